// Round 6
// baseline (159.636 us; speedup 1.0000x reference)
//
#include <hip/hip_runtime.h>
#include <hip/hip_bf16.h>

// Fused recurrent net, 16x16x32 MFMA, 16 rows/wave.
// All matmuls as C^T = W * act^T (col = batch row = lane&15 everywhere).
// - Activations: register-resident; C/D -> B-frag remap via
//   v_permlane32_swap_b32 + v_permlane16_swap_b32 (verified R4/R5).
// - Hot-loop weights (WI2E, WE2I): frag-packed bf16 LDS, conflict-free
//   (verified R2/R5), 32 KB/block.
// - Cold weights (Win2E, WE2Out): streamed from L2 once per wave.
// - __launch_bounds__(512, 2): 2nd arg is MIN BLOCKS PER CU on this hipcc
//   (R1/R3/R5 evidence: (512,2)->120 VGPR, (512,4)->64, default->64).
//   2 blocks x 8 waves = 16 waves/CU = 4 waves/SIMD at 128-VGPR cap.

typedef __bf16 bf16x8_t __attribute__((ext_vector_type(8)));
typedef float f32x4_t __attribute__((ext_vector_type(4)));
typedef unsigned int uintx4_t __attribute__((ext_vector_type(4)));

#define THREADS 512

// Frag-packed bf16 LDS: frag fi for lane l at (fi*64 + l)*16 bytes.
#define OFF_WI2E 0       // 8mt x 2ks = 16 frags -> 16 KB
#define OFF_WE2I 16384   // 4mt x 4ks = 16 frags -> 16 KB
#define SMEM_TOTAL 32768

__device__ __forceinline__ f32x4_t mfma16(bf16x8_t a, bf16x8_t b, f32x4_t c) {
  return __builtin_amdgcn_mfma_f32_16x16x32_bf16(a, b, c, 0, 0, 0);
}

__device__ __forceinline__ void swap32(unsigned int& x, unsigned int& y) {
  asm("v_permlane32_swap_b32 %0, %1" : "+v"(x), "+v"(y));
}
__device__ __forceinline__ void swap16(unsigned int& x, unsigned int& y) {
  asm("v_permlane16_swap_b32 %0, %1" : "+v"(x), "+v"(y));
}

__device__ __forceinline__ unsigned int pack2_relu(float a, float b) {
  unsigned short lo = __builtin_bit_cast(unsigned short, (__bf16)fmaxf(a, 0.f));
  unsigned short hi = __builtin_bit_cast(unsigned short, (__bf16)fmaxf(b, 0.f));
  return (unsigned int)lo | ((unsigned int)hi << 16);
}

// Two 16x16 C/D tiles (features f..f+15, f+16..f+31) -> one B-frag for the
// 32-wide k-step, relu applied.  Verified R4/R5 (absmax 9.8e-4).
__device__ __forceinline__ bf16x8_t remap2(const f32x4_t& t0,
                                           const f32x4_t& t1) {
  unsigned int A0 = pack2_relu(t0[0], t0[1]);
  unsigned int A1 = pack2_relu(t0[2], t0[3]);
  unsigned int B0 = pack2_relu(t1[0], t1[1]);
  unsigned int B1 = pack2_relu(t1[2], t1[3]);
  swap32(A0, B0);
  swap16(A0, B0);
  swap32(A1, B1);
  swap16(A1, B1);
  return __builtin_bit_cast(bf16x8_t, (uintx4_t){A0, A1, B0, B1});
}

__device__ __forceinline__ bf16x8_t cvt8(float4 v0, float4 v1) {
  bf16x8_t h;
  h[0] = (__bf16)v0.x; h[1] = (__bf16)v0.y;
  h[2] = (__bf16)v0.z; h[3] = (__bf16)v0.w;
  h[4] = (__bf16)v1.x; h[5] = (__bf16)v1.y;
  h[6] = (__bf16)v1.z; h[7] = (__bf16)v1.w;
  return h;
}

// A-frag streamed from row-major fp32 W: lane holds
// W[mt*16 + (lane&15)][s*32 + (lane>>4)*8 + j], j=0..7.
__device__ __forceinline__ bf16x8_t gfrag(const float* __restrict__ W,
                                          int off) {
  float4 v0 = *reinterpret_cast<const float4*>(W + off);
  float4 v1 = *reinterpret_cast<const float4*>(W + off + 4);
  return cvt8(v0, v1);
}

__device__ __forceinline__ bf16x8_t ldsfrag(const char* smem, int off, int fi,
                                            int lane) {
  return *reinterpret_cast<const bf16x8_t*>(smem + off + (fi * 64 + lane) * 16);
}

// Stage one weight matrix into frag-packed bf16 LDS (conflict-free).
template <int NMT, int NKS, int COLS>
__device__ __forceinline__ void stage_frags(const float* __restrict__ W,
                                            char* dst, int tid) {
  constexpr int SLOTS = NMT * NKS * 64;
#pragma unroll
  for (int it = 0; it < SLOTS / THREADS; ++it) {
    int slot = it * THREADS + tid;
    int lane = slot & 63;
    int fi = slot >> 6;
    int mt = fi / NKS, ks = fi % NKS;
    int cc = lane & 15, hh = lane >> 4;
    const float* src = W + (mt * 16 + cc) * COLS + ks * 32 + hh * 8;
    float4 v0 = *reinterpret_cast<const float4*>(src);
    float4 v1 = *reinterpret_cast<const float4*>(src + 4);
    *reinterpret_cast<bf16x8_t*>(dst + slot * 16) = cvt8(v0, v1);
  }
}

__global__ __launch_bounds__(THREADS, 2) void unet_fused(
    const float* __restrict__ x,
    const float* __restrict__ Win2E,
    const float* __restrict__ WI2E,
    const float* __restrict__ WE2I,
    const float* __restrict__ WE2Out,
    const int* __restrict__ Tptr,
    float* __restrict__ out) {
  __shared__ __align__(16) char smem[SMEM_TOTAL];
  const int tid = threadIdx.x;

  stage_frags<8, 2, 64>(WI2E, smem + OFF_WI2E, tid);
  stage_frags<4, 4, 128>(WE2I, smem + OFF_WE2I, tid);

  const int wid = tid >> 6, lane = tid & 63;
  const int c = lane & 15, q = lane >> 4;
  const int T = *Tptr;
  const long row0 = ((long)blockIdx.x * 8 + wid) * 16;
  const f32x4_t Z = {};

  // x loads (HBM/L3) issued before the barrier to hide latency.
  const float* xrow = x + (row0 + c) * 128 + q * 8;
  float4 xv[8];
#pragma unroll
  for (int s = 0; s < 4; ++s) {
    xv[2 * s] = *reinterpret_cast<const float4*>(xrow + s * 32);
    xv[2 * s + 1] = *reinterpret_cast<const float4*>(xrow + s * 32 + 4);
  }
  bf16x8_t xb[4];
#pragma unroll
  for (int s = 0; s < 4; ++s) xb[s] = cvt8(xv[2 * s], xv[2 * s + 1]);

  __syncthreads();

  // ff^T = Win2E * x^T (Win2E streamed from L2), f32 for the whole kernel.
  f32x4_t ff[8];
#pragma unroll
  for (int mt = 0; mt < 8; ++mt)
    ff[mt] = mfma16(gfrag(Win2E, (mt * 16 + c) * 128 + q * 8), xb[0], Z);
#pragma unroll
  for (int s = 1; s < 4; ++s)
#pragma unroll
    for (int mt = 0; mt < 8; ++mt)
      ff[mt] = mfma16(gfrag(Win2E, (mt * 16 + c) * 128 + s * 32 + q * 8),
                      xb[s], ff[mt]);

  f32x4_t acc_e[8];
#pragma unroll
  for (int mt = 0; mt < 8; ++mt) acc_e[mt] = ff[mt];  // step 0: actI = 0

  // T-1 full steps; weights via conflict-free ds_read_b128, acts in regs.
  for (int t = 0; t < T - 1; ++t) {
    f32x4_t acc_i[4];
#pragma unroll
    for (int s = 0; s < 4; ++s) {
      bf16x8_t ebs = remap2(acc_e[2 * s], acc_e[2 * s + 1]);
#pragma unroll
      for (int mt = 0; mt < 4; ++mt)
        acc_i[mt] = mfma16(ldsfrag(smem, OFF_WE2I, mt * 4 + s, lane), ebs,
                           s == 0 ? Z : acc_i[mt]);
    }
#pragma unroll
    for (int s = 0; s < 2; ++s) {
      bf16x8_t ibs = remap2(acc_i[2 * s], acc_i[2 * s + 1]);
#pragma unroll
      for (int mt = 0; mt < 8; ++mt)
        acc_e[mt] = mfma16(ldsfrag(smem, OFF_WI2E, mt * 2 + s, lane), ibs,
                           s == 0 ? ff[mt] : acc_e[mt]);
    }
  }

  // out^T = relu(WE2Out * relu(acc_e)^T), WE2Out streamed from L2.
  bf16x8_t eb[4];
#pragma unroll
  for (int s = 0; s < 4; ++s) eb[s] = remap2(acc_e[2 * s], acc_e[2 * s + 1]);
#pragma unroll
  for (int mt = 0; mt < 8; ++mt) {
    f32x4_t o = mfma16(gfrag(WE2Out, (mt * 16 + c) * 128 + q * 8), eb[0], Z);
#pragma unroll
    for (int s = 1; s < 4; ++s)
      o = mfma16(gfrag(WE2Out, (mt * 16 + c) * 128 + s * 32 + q * 8), eb[s], o);
    f32x4_t r;
#pragma unroll
    for (int j = 0; j < 4; ++j) r[j] = fmaxf(o[j], 0.f);
    *reinterpret_cast<f32x4_t*>(out + (row0 + c) * 128 + mt * 16 + q * 4) = r;
  }
}

extern "C" void kernel_launch(void* const* d_in, const int* in_sizes, int n_in,
                              void* d_out, int out_size, void* d_ws,
                              size_t ws_size, hipStream_t stream) {
  const float* x = (const float*)d_in[0];
  const float* Win2E = (const float*)d_in[1];
  const float* WI2E = (const float*)d_in[2];
  const float* WE2I = (const float*)d_in[3];
  const float* WE2Out = (const float*)d_in[4];
  const int* Tptr = (const int*)d_in[5];
  float* out = (float*)d_out;
  (void)n_in; (void)out_size; (void)d_ws; (void)ws_size;

  const int B = in_sizes[0] / 128;  // 131072
  dim3 grid(B / 128), block(THREADS);
  unet_fused<<<grid, block, 0, stream>>>(x, Win2E, WI2E, WE2I, WE2Out, Tptr,
                                         out);
}

// Round 7
// 77.134 us; speedup vs baseline: 2.0696x; 2.0696x over previous
//
#include <hip/hip_runtime.h>
#include <hip/hip_bf16.h>

// Fused recurrent net, 16x16x32 MFMA, 16 rows/wave.
// R7 synthesis:
//  - ALL 4 weights staged frag-packed bf16 in LDS once per block (96 KB,
//    conflict-free b128; layout verified R2/R5/R6) -> global weight traffic
//    O(once per block), not per-wave (R4/R6's 2 GB L2 mistake).
//  - Hot-loop weights WI2E/WE2I hoisted LDS -> 128 VGPRs (R1-verified).
//  - t-loop: ZERO memory ops, zero barriers. Activations live in registers;
//    C/D -> B-frag remap via permlane32+16 swaps (verified R4/R5/R6).
//  - __launch_bounds__(512,2): 2 waves/EU -> 256-reg budget; peak live ~240.
//  - Cold weights (Win2E ff phase, WE2Out out phase) read from LDS frags.

typedef __bf16 bf16x8_t __attribute__((ext_vector_type(8)));
typedef float f32x4_t __attribute__((ext_vector_type(4)));
typedef unsigned int uintx4_t __attribute__((ext_vector_type(4)));

#define THREADS 512

// Frag-packed bf16 LDS: frag fi for lane l at base + (fi*64 + l)*16 bytes.
#define OFF_WIN2E 0        // 8mt x 4ks = 32 frags -> 32 KB
#define OFF_WI2E 32768     // 8mt x 2ks = 16 frags -> 16 KB
#define OFF_WE2I 49152     // 4mt x 4ks = 16 frags -> 16 KB
#define OFF_WE2OUT 65536   // 8mt x 4ks = 32 frags -> 32 KB
#define SMEM_TOTAL 98304

__device__ __forceinline__ f32x4_t mfma16(bf16x8_t a, bf16x8_t b, f32x4_t c) {
  return __builtin_amdgcn_mfma_f32_16x16x32_bf16(a, b, c, 0, 0, 0);
}

__device__ __forceinline__ void swap32(unsigned int& x, unsigned int& y) {
  asm("v_permlane32_swap_b32 %0, %1" : "+v"(x), "+v"(y));
}
__device__ __forceinline__ void swap16(unsigned int& x, unsigned int& y) {
  asm("v_permlane16_swap_b32 %0, %1" : "+v"(x), "+v"(y));
}

__device__ __forceinline__ unsigned int pack2_relu(float a, float b) {
  unsigned short lo = __builtin_bit_cast(unsigned short, (__bf16)fmaxf(a, 0.f));
  unsigned short hi = __builtin_bit_cast(unsigned short, (__bf16)fmaxf(b, 0.f));
  return (unsigned int)lo | ((unsigned int)hi << 16);
}

// Two 16x16 C/D tiles (features f..f+15, f+16..f+31) -> one B-frag for the
// 32-wide k-step, relu applied.  Verified R4/R5/R6 (absmax 9.8e-4).
__device__ __forceinline__ bf16x8_t remap2(const f32x4_t& t0,
                                           const f32x4_t& t1) {
  unsigned int A0 = pack2_relu(t0[0], t0[1]);
  unsigned int A1 = pack2_relu(t0[2], t0[3]);
  unsigned int B0 = pack2_relu(t1[0], t1[1]);
  unsigned int B1 = pack2_relu(t1[2], t1[3]);
  swap32(A0, B0);
  swap16(A0, B0);
  swap32(A1, B1);
  swap16(A1, B1);
  return __builtin_bit_cast(bf16x8_t, (uintx4_t){A0, A1, B0, B1});
}

__device__ __forceinline__ bf16x8_t cvt8(float4 v0, float4 v1) {
  bf16x8_t h;
  h[0] = (__bf16)v0.x; h[1] = (__bf16)v0.y;
  h[2] = (__bf16)v0.z; h[3] = (__bf16)v0.w;
  h[4] = (__bf16)v1.x; h[5] = (__bf16)v1.y;
  h[6] = (__bf16)v1.z; h[7] = (__bf16)v1.w;
  return h;
}

__device__ __forceinline__ bf16x8_t ldsfrag(const char* smem, int off, int fi,
                                            int lane) {
  return *reinterpret_cast<const bf16x8_t*>(smem + off + (fi * 64 + lane) * 16);
}

// Stage one weight matrix into frag-packed bf16 LDS (conflict-free).
// Frag fi = mt*NKS + ks; lane l holds W[mt*16+(l&15)][ks*32+(l>>4)*8 + j].
template <int NMT, int NKS, int COLS>
__device__ __forceinline__ void stage_frags(const float* __restrict__ W,
                                            char* dst, int tid) {
  constexpr int SLOTS = NMT * NKS * 64;
#pragma unroll
  for (int it = 0; it < SLOTS / THREADS; ++it) {
    int slot = it * THREADS + tid;
    int lane = slot & 63;
    int fi = slot >> 6;
    int mt = fi / NKS, ks = fi % NKS;
    int cc = lane & 15, hh = lane >> 4;
    const float* src = W + (mt * 16 + cc) * COLS + ks * 32 + hh * 8;
    float4 v0 = *reinterpret_cast<const float4*>(src);
    float4 v1 = *reinterpret_cast<const float4*>(src + 4);
    *reinterpret_cast<bf16x8_t*>(dst + slot * 16) = cvt8(v0, v1);
  }
}

__global__ __launch_bounds__(THREADS, 2) void unet_fused(
    const float* __restrict__ x,
    const float* __restrict__ Win2E,
    const float* __restrict__ WI2E,
    const float* __restrict__ WE2I,
    const float* __restrict__ WE2Out,
    const int* __restrict__ Tptr,
    float* __restrict__ out) {
  extern __shared__ char smem[];
  const int tid = threadIdx.x;

  stage_frags<8, 4, 128>(Win2E, smem + OFF_WIN2E, tid);
  stage_frags<8, 2, 64>(WI2E, smem + OFF_WI2E, tid);
  stage_frags<4, 4, 128>(WE2I, smem + OFF_WE2I, tid);
  stage_frags<8, 4, 128>(WE2Out, smem + OFF_WE2OUT, tid);

  const int wid = tid >> 6, lane = tid & 63;
  const int c = lane & 15, q = lane >> 4;
  const int T = *Tptr;
  const long row0 = ((long)blockIdx.x * 8 + wid) * 16;
  const f32x4_t Z = {};

  // x loads issued before the barrier so HBM latency hides under staging.
  const float* xrow = x + (row0 + c) * 128 + q * 8;
  float4 xv[8];
#pragma unroll
  for (int s = 0; s < 4; ++s) {
    xv[2 * s] = *reinterpret_cast<const float4*>(xrow + s * 32);
    xv[2 * s + 1] = *reinterpret_cast<const float4*>(xrow + s * 32 + 4);
  }

  __syncthreads();

  bf16x8_t xb[4];
#pragma unroll
  for (int s = 0; s < 4; ++s) xb[s] = cvt8(xv[2 * s], xv[2 * s + 1]);

  // ff^T = Win2E * x^T (Win2E frags from LDS), f32 for the whole kernel.
  f32x4_t ff[8];
#pragma unroll
  for (int mt = 0; mt < 8; ++mt)
    ff[mt] = mfma16(ldsfrag(smem, OFF_WIN2E, mt * 4 + 0, lane), xb[0], Z);
#pragma unroll
  for (int s = 1; s < 4; ++s)
#pragma unroll
    for (int mt = 0; mt < 8; ++mt)
      ff[mt] = mfma16(ldsfrag(smem, OFF_WIN2E, mt * 4 + s, lane), xb[s], ff[mt]);

  // Hoist hot-loop weights LDS -> registers (128 VGPRs), reused T-1 times.
  bf16x8_t wi2e[8][2];
#pragma unroll
  for (int mt = 0; mt < 8; ++mt)
#pragma unroll
    for (int s = 0; s < 2; ++s)
      wi2e[mt][s] = ldsfrag(smem, OFF_WI2E, mt * 2 + s, lane);
  bf16x8_t we2i[4][4];
#pragma unroll
  for (int mt = 0; mt < 4; ++mt)
#pragma unroll
    for (int s = 0; s < 4; ++s)
      we2i[mt][s] = ldsfrag(smem, OFF_WE2I, mt * 4 + s, lane);

  f32x4_t acc_e[8];
#pragma unroll
  for (int mt = 0; mt < 8; ++mt) acc_e[mt] = ff[mt];  // step 0: actI = 0

  // T-1 full steps: pure MFMA + VALU, zero memory ops, zero barriers.
  for (int t = 0; t < T - 1; ++t) {
    f32x4_t acc_i[4];
#pragma unroll
    for (int s = 0; s < 4; ++s) {
      bf16x8_t ebs = remap2(acc_e[2 * s], acc_e[2 * s + 1]);
#pragma unroll
      for (int mt = 0; mt < 4; ++mt)
        acc_i[mt] = mfma16(we2i[mt][s], ebs, s == 0 ? Z : acc_i[mt]);
    }
#pragma unroll
    for (int s = 0; s < 2; ++s) {
      bf16x8_t ibs = remap2(acc_i[2 * s], acc_i[2 * s + 1]);
#pragma unroll
      for (int mt = 0; mt < 8; ++mt)
        acc_e[mt] = mfma16(wi2e[mt][s], ibs, s == 0 ? ff[mt] : acc_e[mt]);
    }
  }

  // out^T = relu(WE2Out * relu(acc_e)^T), WE2Out frags from LDS.
  bf16x8_t eb[4];
#pragma unroll
  for (int s = 0; s < 4; ++s) eb[s] = remap2(acc_e[2 * s], acc_e[2 * s + 1]);
#pragma unroll
  for (int mt = 0; mt < 8; ++mt) {
    f32x4_t o = mfma16(ldsfrag(smem, OFF_WE2OUT, mt * 4 + 0, lane), eb[0], Z);
#pragma unroll
    for (int s = 1; s < 4; ++s)
      o = mfma16(ldsfrag(smem, OFF_WE2OUT, mt * 4 + s, lane), eb[s], o);
    f32x4_t r;
#pragma unroll
    for (int j = 0; j < 4; ++j) r[j] = fmaxf(o[j], 0.f);
    *reinterpret_cast<f32x4_t*>(out + (row0 + c) * 128 + mt * 16 + q * 4) = r;
  }
}

extern "C" void kernel_launch(void* const* d_in, const int* in_sizes, int n_in,
                              void* d_out, int out_size, void* d_ws,
                              size_t ws_size, hipStream_t stream) {
  const float* x = (const float*)d_in[0];
  const float* Win2E = (const float*)d_in[1];
  const float* WI2E = (const float*)d_in[2];
  const float* WE2I = (const float*)d_in[3];
  const float* WE2Out = (const float*)d_in[4];
  const int* Tptr = (const int*)d_in[5];
  float* out = (float*)d_out;
  (void)n_in; (void)out_size; (void)d_ws; (void)ws_size;

  const int B = in_sizes[0] / 128;  // 131072
  (void)hipFuncSetAttribute(reinterpret_cast<const void*>(unet_fused),
                            hipFuncAttributeMaxDynamicSharedMemorySize,
                            SMEM_TOTAL);
  dim3 grid(B / 128), block(THREADS);
  unet_fused<<<grid, block, SMEM_TOTAL, stream>>>(x, Win2E, WI2E, WE2I, WE2Out,
                                                  Tptr, out);
}

// Round 8
// 68.445 us; speedup vs baseline: 2.3323x; 1.1269x over previous
//
#include <hip/hip_runtime.h>
#include <hip/hip_bf16.h>

// Fused recurrent net, 16x16x32 MFMA.
// R8: TWO independent 16-row batch tiles per wave (ILP x2 to fill the MFMA
// pipe at the 2-waves/SIMD occupancy that 96 KB LDS + 256-reg budget force).
//  - ALL 4 weights staged frag-packed bf16 in LDS once per block (96 KB,
//    conflict-free b128; verified R2..R7).
//  - NO weight hoisting (R3/R4/R5 spill lessons): every weight frag is
//    ds_read once per step and feeds BOTH tiles' MFMAs.
//  - Activations register-resident; C/D -> B-frag remap via
//    permlane32+permlane16 swaps (verified R4..R7).  ~190 live regs.

typedef __bf16 bf16x8_t __attribute__((ext_vector_type(8)));
typedef float f32x4_t __attribute__((ext_vector_type(4)));
typedef unsigned int uintx4_t __attribute__((ext_vector_type(4)));

#define THREADS 512

// Frag-packed bf16 LDS: frag fi for lane l at base + (fi*64 + l)*16 bytes.
#define OFF_WIN2E 0        // 8mt x 4ks = 32 frags -> 32 KB
#define OFF_WI2E 32768     // 8mt x 2ks = 16 frags -> 16 KB
#define OFF_WE2I 49152     // 4mt x 4ks = 16 frags -> 16 KB
#define OFF_WE2OUT 65536   // 8mt x 4ks = 32 frags -> 32 KB
#define SMEM_TOTAL 98304

__device__ __forceinline__ f32x4_t mfma16(bf16x8_t a, bf16x8_t b, f32x4_t c) {
  return __builtin_amdgcn_mfma_f32_16x16x32_bf16(a, b, c, 0, 0, 0);
}

__device__ __forceinline__ void swap32(unsigned int& x, unsigned int& y) {
  asm("v_permlane32_swap_b32 %0, %1" : "+v"(x), "+v"(y));
}
__device__ __forceinline__ void swap16(unsigned int& x, unsigned int& y) {
  asm("v_permlane16_swap_b32 %0, %1" : "+v"(x), "+v"(y));
}

__device__ __forceinline__ unsigned int pack2_relu(float a, float b) {
  unsigned short lo = __builtin_bit_cast(unsigned short, (__bf16)fmaxf(a, 0.f));
  unsigned short hi = __builtin_bit_cast(unsigned short, (__bf16)fmaxf(b, 0.f));
  return (unsigned int)lo | ((unsigned int)hi << 16);
}

// Two 16x16 C/D tiles (features f..f+15, f+16..f+31) -> one B-frag for the
// 32-wide k-step, relu applied.  Verified R4..R7 (absmax 9.8e-4).
__device__ __forceinline__ bf16x8_t remap2(const f32x4_t& t0,
                                           const f32x4_t& t1) {
  unsigned int A0 = pack2_relu(t0[0], t0[1]);
  unsigned int A1 = pack2_relu(t0[2], t0[3]);
  unsigned int B0 = pack2_relu(t1[0], t1[1]);
  unsigned int B1 = pack2_relu(t1[2], t1[3]);
  swap32(A0, B0);
  swap16(A0, B0);
  swap32(A1, B1);
  swap16(A1, B1);
  return __builtin_bit_cast(bf16x8_t, (uintx4_t){A0, A1, B0, B1});
}

__device__ __forceinline__ bf16x8_t cvt8(float4 v0, float4 v1) {
  bf16x8_t h;
  h[0] = (__bf16)v0.x; h[1] = (__bf16)v0.y;
  h[2] = (__bf16)v0.z; h[3] = (__bf16)v0.w;
  h[4] = (__bf16)v1.x; h[5] = (__bf16)v1.y;
  h[6] = (__bf16)v1.z; h[7] = (__bf16)v1.w;
  return h;
}

__device__ __forceinline__ bf16x8_t ldsfrag(const char* smem, int off, int fi,
                                            int lane) {
  return *reinterpret_cast<const bf16x8_t*>(smem + off + (fi * 64 + lane) * 16);
}

// Stage one weight matrix into frag-packed bf16 LDS (conflict-free).
// Frag fi = mt*NKS + ks; lane l holds W[mt*16+(l&15)][ks*32+(l>>4)*8 + j].
template <int NMT, int NKS, int COLS>
__device__ __forceinline__ void stage_frags(const float* __restrict__ W,
                                            char* dst, int tid) {
  constexpr int SLOTS = NMT * NKS * 64;
#pragma unroll
  for (int it = 0; it < SLOTS / THREADS; ++it) {
    int slot = it * THREADS + tid;
    int lane = slot & 63;
    int fi = slot >> 6;
    int mt = fi / NKS, ks = fi % NKS;
    int cc = lane & 15, hh = lane >> 4;
    const float* src = W + (mt * 16 + cc) * COLS + ks * 32 + hh * 8;
    float4 v0 = *reinterpret_cast<const float4*>(src);
    float4 v1 = *reinterpret_cast<const float4*>(src + 4);
    *reinterpret_cast<bf16x8_t*>(dst + slot * 16) = cvt8(v0, v1);
  }
}

__global__ __launch_bounds__(THREADS, 2) void unet_fused(
    const float* __restrict__ x,
    const float* __restrict__ Win2E,
    const float* __restrict__ WI2E,
    const float* __restrict__ WE2I,
    const float* __restrict__ WE2Out,
    const int* __restrict__ Tptr,
    float* __restrict__ out) {
  extern __shared__ char smem[];
  const int tid = threadIdx.x;

  stage_frags<8, 4, 128>(Win2E, smem + OFF_WIN2E, tid);
  stage_frags<8, 2, 64>(WI2E, smem + OFF_WI2E, tid);
  stage_frags<4, 4, 128>(WE2I, smem + OFF_WE2I, tid);
  stage_frags<8, 4, 128>(WE2Out, smem + OFF_WE2OUT, tid);

  const int wid = tid >> 6, lane = tid & 63;
  const int c = lane & 15, q = lane >> 4;
  const int T = *Tptr;
  // Two 16-row tiles per wave: rows base+0..15 (u=0), base+16..31 (u=1).
  const long base = ((long)blockIdx.x * 8 + wid) * 32;
  const f32x4_t Z = {};

  // x loads for both tiles, issued before the barrier (hide under staging).
  float4 xv[2][8];
#pragma unroll
  for (int u = 0; u < 2; ++u) {
    const float* xrow = x + (base + u * 16 + c) * 128 + q * 8;
#pragma unroll
    for (int s = 0; s < 4; ++s) {
      xv[u][2 * s] = *reinterpret_cast<const float4*>(xrow + s * 32);
      xv[u][2 * s + 1] = *reinterpret_cast<const float4*>(xrow + s * 32 + 4);
    }
  }

  __syncthreads();

  bf16x8_t xb[2][4];
#pragma unroll
  for (int u = 0; u < 2; ++u)
#pragma unroll
    for (int s = 0; s < 4; ++s)
      xb[u][s] = cvt8(xv[u][2 * s], xv[u][2 * s + 1]);

  // ff^T = Win2E * x^T; each Win2E frag read once, feeds both tiles.
  f32x4_t ff[2][8];
#pragma unroll
  for (int s = 0; s < 4; ++s)
#pragma unroll
    for (int mt = 0; mt < 8; ++mt) {
      bf16x8_t a = ldsfrag(smem, OFF_WIN2E, mt * 4 + s, lane);
#pragma unroll
      for (int u = 0; u < 2; ++u)
        ff[u][mt] = mfma16(a, xb[u][s], s == 0 ? Z : ff[u][mt]);
    }

  f32x4_t acc_e[2][8];
#pragma unroll
  for (int u = 0; u < 2; ++u)
#pragma unroll
    for (int mt = 0; mt < 8; ++mt) acc_e[u][mt] = ff[u][mt];  // actI = 0

  // T-1 steps: weights via shared conflict-free ds_read_b128; two
  // independent MFMA/VALU chains per wave hide each other's latency.
  for (int t = 0; t < T - 1; ++t) {
    f32x4_t acc_i[2][4];
#pragma unroll
    for (int s = 0; s < 4; ++s) {
      bf16x8_t e0 = remap2(acc_e[0][2 * s], acc_e[0][2 * s + 1]);
      bf16x8_t e1 = remap2(acc_e[1][2 * s], acc_e[1][2 * s + 1]);
#pragma unroll
      for (int mt = 0; mt < 4; ++mt) {
        bf16x8_t a = ldsfrag(smem, OFF_WE2I, mt * 4 + s, lane);
        acc_i[0][mt] = mfma16(a, e0, s == 0 ? Z : acc_i[0][mt]);
        acc_i[1][mt] = mfma16(a, e1, s == 0 ? Z : acc_i[1][mt]);
      }
    }
#pragma unroll
    for (int s = 0; s < 2; ++s) {
      bf16x8_t i0 = remap2(acc_i[0][2 * s], acc_i[0][2 * s + 1]);
      bf16x8_t i1 = remap2(acc_i[1][2 * s], acc_i[1][2 * s + 1]);
#pragma unroll
      for (int mt = 0; mt < 8; ++mt) {
        bf16x8_t a = ldsfrag(smem, OFF_WI2E, mt * 2 + s, lane);
        acc_e[0][mt] = mfma16(a, i0, s == 0 ? ff[0][mt] : acc_e[0][mt]);
        acc_e[1][mt] = mfma16(a, i1, s == 0 ? ff[1][mt] : acc_e[1][mt]);
      }
    }
  }

  // out^T = relu(WE2Out * relu(acc_e)^T); frags shared across tiles.
  bf16x8_t eb[2][4];
#pragma unroll
  for (int u = 0; u < 2; ++u)
#pragma unroll
    for (int s = 0; s < 4; ++s)
      eb[u][s] = remap2(acc_e[u][2 * s], acc_e[u][2 * s + 1]);
#pragma unroll
  for (int mt = 0; mt < 8; ++mt) {
    f32x4_t o[2] = {Z, Z};
#pragma unroll
    for (int s = 0; s < 4; ++s) {
      bf16x8_t a = ldsfrag(smem, OFF_WE2OUT, mt * 4 + s, lane);
#pragma unroll
      for (int u = 0; u < 2; ++u) o[u] = mfma16(a, eb[u][s], o[u]);
    }
#pragma unroll
    for (int u = 0; u < 2; ++u) {
      f32x4_t r;
#pragma unroll
      for (int j = 0; j < 4; ++j) r[j] = fmaxf(o[u][j], 0.f);
      *reinterpret_cast<f32x4_t*>(out + (base + u * 16 + c) * 128 + mt * 16 +
                                  q * 4) = r;
    }
  }
}

extern "C" void kernel_launch(void* const* d_in, const int* in_sizes, int n_in,
                              void* d_out, int out_size, void* d_ws,
                              size_t ws_size, hipStream_t stream) {
  const float* x = (const float*)d_in[0];
  const float* Win2E = (const float*)d_in[1];
  const float* WI2E = (const float*)d_in[2];
  const float* WE2I = (const float*)d_in[3];
  const float* WE2Out = (const float*)d_in[4];
  const int* Tptr = (const int*)d_in[5];
  float* out = (float*)d_out;
  (void)n_in; (void)out_size; (void)d_ws; (void)ws_size;

  const int B = in_sizes[0] / 128;  // 131072
  (void)hipFuncSetAttribute(reinterpret_cast<const void*>(unet_fused),
                            hipFuncAttributeMaxDynamicSharedMemorySize,
                            SMEM_TOTAL);
  dim3 grid(B / 256), block(THREADS);
  unet_fused<<<grid, block, SMEM_TOTAL, stream>>>(x, Win2E, WI2E, WE2I, WE2Out,
                                                  Tptr, out);
}

// Round 10
// 62.322 us; speedup vs baseline: 2.5615x; 1.0982x over previous
//
#include <hip/hip_runtime.h>
#include <hip/hip_bf16.h>

// Fused recurrent net, 16x16x32 MFMA, 16 rows/wave.
// R9 (resubmit; container died before the first run): fit the whole working
// set in a 128-reg/lane budget so occupancy can double (4 waves/SIMD):
//  - ff kept in bf16 (16 arch regs), unpacked per step (1 VALU/val, exact).
//    Accums: acc_e(32) + acc_i(16) = 48 <= 64 AGPR half.
//  - LDS 64 KB: Win2E / WE2Out TIME-SHARE one 32 KB slot. WE2Out staging is
//    issued right after the ff phase; its latency hides under the t-loop.
//    64 KB -> 2 blocks/CU; __launch_bounds__(512,4) -> 16 waves/CU.
//  - Otherwise R7 dataflow: frag-packed conflict-free weight LDS (R2..R8),
//    register-resident activations, permlane32+16 remap (R4..R8).

typedef __bf16 bf16x8_t __attribute__((ext_vector_type(8)));
typedef float f32x4_t __attribute__((ext_vector_type(4)));
typedef unsigned int uintx4_t __attribute__((ext_vector_type(4)));

#define THREADS 512

// Frag-packed bf16 LDS: frag fi for lane l at base + (fi*64 + l)*16 bytes.
#define OFF_COLD 0         // 32 KB: Win2E (ff phase), then WE2Out (out phase)
#define OFF_WI2E 32768     // 8mt x 2ks = 16 frags -> 16 KB
#define OFF_WE2I 49152     // 4mt x 4ks = 16 frags -> 16 KB
#define SMEM_TOTAL 65536

__device__ __forceinline__ f32x4_t mfma16(bf16x8_t a, bf16x8_t b, f32x4_t c) {
  return __builtin_amdgcn_mfma_f32_16x16x32_bf16(a, b, c, 0, 0, 0);
}

__device__ __forceinline__ void swap32(unsigned int& x, unsigned int& y) {
  asm("v_permlane32_swap_b32 %0, %1" : "+v"(x), "+v"(y));
}
__device__ __forceinline__ void swap16(unsigned int& x, unsigned int& y) {
  asm("v_permlane16_swap_b32 %0, %1" : "+v"(x), "+v"(y));
}

__device__ __forceinline__ unsigned int pack2_relu(float a, float b) {
  unsigned short lo = __builtin_bit_cast(unsigned short, (__bf16)fmaxf(a, 0.f));
  unsigned short hi = __builtin_bit_cast(unsigned short, (__bf16)fmaxf(b, 0.f));
  return (unsigned int)lo | ((unsigned int)hi << 16);
}
__device__ __forceinline__ unsigned int pack2(float a, float b) {
  unsigned short lo = __builtin_bit_cast(unsigned short, (__bf16)a);
  unsigned short hi = __builtin_bit_cast(unsigned short, (__bf16)b);
  return (unsigned int)lo | ((unsigned int)hi << 16);
}
// Exact bf16->f32 unpack of two packed pairs into C/D-ordered f32x4.
__device__ __forceinline__ f32x4_t unpack4(unsigned int u0, unsigned int u1) {
  f32x4_t r;
  r[0] = __builtin_bit_cast(float, u0 << 16);
  r[1] = __builtin_bit_cast(float, u0 & 0xffff0000u);
  r[2] = __builtin_bit_cast(float, u1 << 16);
  r[3] = __builtin_bit_cast(float, u1 & 0xffff0000u);
  return r;
}

// Two 16x16 C/D tiles -> one B-frag for the 32-wide k-step, relu applied.
// Verified R4..R8 (absmax 9.8e-4).
__device__ __forceinline__ bf16x8_t remap2(const f32x4_t& t0,
                                           const f32x4_t& t1) {
  unsigned int A0 = pack2_relu(t0[0], t0[1]);
  unsigned int A1 = pack2_relu(t0[2], t0[3]);
  unsigned int B0 = pack2_relu(t1[0], t1[1]);
  unsigned int B1 = pack2_relu(t1[2], t1[3]);
  swap32(A0, B0);
  swap16(A0, B0);
  swap32(A1, B1);
  swap16(A1, B1);
  return __builtin_bit_cast(bf16x8_t, (uintx4_t){A0, A1, B0, B1});
}

__device__ __forceinline__ bf16x8_t cvt8(float4 v0, float4 v1) {
  bf16x8_t h;
  h[0] = (__bf16)v0.x; h[1] = (__bf16)v0.y;
  h[2] = (__bf16)v0.z; h[3] = (__bf16)v0.w;
  h[4] = (__bf16)v1.x; h[5] = (__bf16)v1.y;
  h[6] = (__bf16)v1.z; h[7] = (__bf16)v1.w;
  return h;
}

__device__ __forceinline__ bf16x8_t ldsfrag(const char* smem, int off, int fi,
                                            int lane) {
  return *reinterpret_cast<const bf16x8_t*>(smem + off + (fi * 64 + lane) * 16);
}

// Stage one weight matrix into frag-packed bf16 LDS (conflict-free).
// Frag fi = mt*NKS + ks; lane l holds W[mt*16+(l&15)][ks*32+(l>>4)*8 + j].
template <int NMT, int NKS, int COLS>
__device__ __forceinline__ void stage_frags(const float* __restrict__ W,
                                            char* dst, int tid) {
  constexpr int SLOTS = NMT * NKS * 64;
#pragma unroll
  for (int it = 0; it < SLOTS / THREADS; ++it) {
    int slot = it * THREADS + tid;
    int lane = slot & 63;
    int fi = slot >> 6;
    int mt = fi / NKS, ks = fi % NKS;
    int cc = lane & 15, hh = lane >> 4;
    const float* src = W + (mt * 16 + cc) * COLS + ks * 32 + hh * 8;
    float4 v0 = *reinterpret_cast<const float4*>(src);
    float4 v1 = *reinterpret_cast<const float4*>(src + 4);
    *reinterpret_cast<bf16x8_t*>(dst + slot * 16) = cvt8(v0, v1);
  }
}

__global__ __launch_bounds__(THREADS, 4) void unet_fused(
    const float* __restrict__ x,
    const float* __restrict__ Win2E,
    const float* __restrict__ WI2E,
    const float* __restrict__ WE2I,
    const float* __restrict__ WE2Out,
    const int* __restrict__ Tptr,
    float* __restrict__ out) {
  extern __shared__ char smem[];
  const int tid = threadIdx.x;

  stage_frags<8, 4, 128>(Win2E, smem + OFF_COLD, tid);
  stage_frags<8, 2, 64>(WI2E, smem + OFF_WI2E, tid);
  stage_frags<4, 4, 128>(WE2I, smem + OFF_WE2I, tid);

  const int wid = tid >> 6, lane = tid & 63;
  const int c = lane & 15, q = lane >> 4;
  const int T = *Tptr;
  const long row0 = ((long)blockIdx.x * 8 + wid) * 16;
  const f32x4_t Z = {};

  // x loads -> bf16 BEFORE the barrier (only 16 regs live across it).
  const float* xrow = x + (row0 + c) * 128 + q * 8;
  bf16x8_t xb[4];
#pragma unroll
  for (int s = 0; s < 4; ++s) {
    float4 v0 = *reinterpret_cast<const float4*>(xrow + s * 32);
    float4 v1 = *reinterpret_cast<const float4*>(xrow + s * 32 + 4);
    xb[s] = cvt8(v0, v1);
  }

  __syncthreads();

  // ff^T = Win2E * x^T from the COLD slot.
  f32x4_t ff[8];
#pragma unroll
  for (int mt = 0; mt < 8; ++mt)
    ff[mt] = mfma16(ldsfrag(smem, OFF_COLD, mt * 4 + 0, lane), xb[0], Z);
#pragma unroll
  for (int s = 1; s < 4; ++s)
#pragma unroll
    for (int mt = 0; mt < 8; ++mt)
      ff[mt] = mfma16(ldsfrag(smem, OFF_COLD, mt * 4 + s, lane), xb[s], ff[mt]);

  __syncthreads();  // everyone done reading Win2E from COLD

  // Re-stage COLD with WE2Out; global latency hides under the t-loop.
  stage_frags<8, 4, 128>(WE2Out, smem + OFF_COLD, tid);

  // Pack ff to bf16 (16 arch regs); seed step 0 from the f32 copy.
  unsigned int ffb[8][2];
  f32x4_t acc_e[8];
#pragma unroll
  for (int mt = 0; mt < 8; ++mt) {
    ffb[mt][0] = pack2(ff[mt][0], ff[mt][1]);
    ffb[mt][1] = pack2(ff[mt][2], ff[mt][3]);
    acc_e[mt] = ff[mt];
  }

  // T-1 steps: weights via conflict-free ds_read_b128, acts in regs,
  // ff re-seeded from bf16 (exact unpack, 1 op/value).
  for (int t = 0; t < T - 1; ++t) {
    f32x4_t acc_i[4];
#pragma unroll
    for (int s = 0; s < 4; ++s) {
      bf16x8_t ebs = remap2(acc_e[2 * s], acc_e[2 * s + 1]);
#pragma unroll
      for (int mt = 0; mt < 4; ++mt)
        acc_i[mt] = mfma16(ldsfrag(smem, OFF_WE2I, mt * 4 + s, lane), ebs,
                           s == 0 ? Z : acc_i[mt]);
    }
#pragma unroll
    for (int mt = 0; mt < 8; ++mt) acc_e[mt] = unpack4(ffb[mt][0], ffb[mt][1]);
#pragma unroll
    for (int s = 0; s < 2; ++s) {
      bf16x8_t ibs = remap2(acc_i[2 * s], acc_i[2 * s + 1]);
#pragma unroll
      for (int mt = 0; mt < 8; ++mt)
        acc_e[mt] =
            mfma16(ldsfrag(smem, OFF_WI2E, mt * 2 + s, lane), ibs, acc_e[mt]);
    }
  }

  __syncthreads();  // WE2Out staging complete & visible

  // out^T = relu(WE2Out * relu(acc_e)^T) from the COLD slot.
  bf16x8_t eb[4];
#pragma unroll
  for (int s = 0; s < 4; ++s) eb[s] = remap2(acc_e[2 * s], acc_e[2 * s + 1]);
#pragma unroll
  for (int mt = 0; mt < 8; ++mt) {
    f32x4_t o = mfma16(ldsfrag(smem, OFF_COLD, mt * 4 + 0, lane), eb[0], Z);
#pragma unroll
    for (int s = 1; s < 4; ++s)
      o = mfma16(ldsfrag(smem, OFF_COLD, mt * 4 + s, lane), eb[s], o);
    f32x4_t r;
#pragma unroll
    for (int j = 0; j < 4; ++j) r[j] = fmaxf(o[j], 0.f);
    *reinterpret_cast<f32x4_t*>(out + (row0 + c) * 128 + mt * 16 + q * 4) = r;
  }
}

extern "C" void kernel_launch(void* const* d_in, const int* in_sizes, int n_in,
                              void* d_out, int out_size, void* d_ws,
                              size_t ws_size, hipStream_t stream) {
  const float* x = (const float*)d_in[0];
  const float* Win2E = (const float*)d_in[1];
  const float* WI2E = (const float*)d_in[2];
  const float* WE2I = (const float*)d_in[3];
  const float* WE2Out = (const float*)d_in[4];
  const int* Tptr = (const int*)d_in[5];
  float* out = (float*)d_out;
  (void)n_in; (void)out_size; (void)d_ws; (void)ws_size;

  const int B = in_sizes[0] / 128;  // 131072
  (void)hipFuncSetAttribute(reinterpret_cast<const void*>(unet_fused),
                            hipFuncAttributeMaxDynamicSharedMemorySize,
                            SMEM_TOTAL);
  dim3 grid(B / 128), block(THREADS);
  unet_fused<<<grid, block, SMEM_TOTAL, stream>>>(x, Win2E, WI2E, WE2I, WE2Out,
                                                  Tptr, out);
}